// Round 1
// baseline (192.286 us; speedup 1.0000x reference)
//
#include <hip/hip_runtime.h>
#include <hip/hip_bf16.h>
#include <math.h>

// ---------------------------------------------------------------------------
// FeatureClustering: fused EMG artifact-model log-likelihood.
//   x = (alt + t) @ Rot^T        (R=65536, E=128 fp32 GEMM, vector-ALU)
//   nonart_r  = c0 - 0.5*sum((x/s)^2)
//   dot_rk    = x . u_k ;  orth2 = ||x||^2 - dot^2   (u unit)
//   art_rk    = orth_ll(orth2) + EMG(dot)
//   segment sums over ragged read sets -> logsumexp -> capped logits
// ---------------------------------------------------------------------------

#define LOG2PI_F 1.8378770664093453f
#define SQRTPI_F 1.7724538509055159f
#define SQRT2_F  1.4142135623730951f

// params block layout (floats), K fixed at 12 for this dataset
#define PP_AK   0     // mu + lambda*sigma^2
#define PP_M2   12    // 2*mu + lambda*sigma^2
#define PP_LT   24    // lambda/2
#define PP_LC   36    // log(lambda/2)
#define PP_ISQ  48    // 1/(sqrt(2)*sigma)
#define PP_I2SA 60    // 1/(2*artifact_stdev^2)
#define PP_OC   72    // orth const
#define PP_LSM  84    // log_softmax(weights)
#define PP_CNA  96    // nonartifact const
#define PP_SIZE 112

__device__ __forceinline__ float logerfc_f(float z) {
    if (z > 5.0f) {
        float z2 = z * z;
        float rz2 = 1.0f / z2;
        float corr = rz2 * (-0.5f + rz2 * (0.75f - 1.875f * rz2));
        return -z2 - logf(z * SQRTPI_F) + log1pf(corr);
    }
    return logf(erfcf(z));
}

// ---------------------------------------------------------------------------
// Setup: normalize directions, per-cluster constants, log_softmax, offsets scan
// ---------------------------------------------------------------------------
__global__ __launch_bounds__(256) void k_setup(
    const float* __restrict__ trans, const float* __restrict__ rot,
    const float* __restrict__ stdev, const float* __restrict__ dirs,
    const float* __restrict__ mu, const float* __restrict__ sigma,
    const float* __restrict__ lam, const float* __restrict__ astd,
    const float* __restrict__ w, const int* __restrict__ counts,
    float* __restrict__ u_n, float* __restrict__ invs2, float* __restrict__ pf,
    int* __restrict__ offs, int B, int R, int E, int K)
{
    const int tid = threadIdx.x;
    const int lane = tid & 63;
    const int wv = tid >> 6;

    // normalize artifact directions (one wave per k, strided)
    for (int k = wv; k < K; k += 4) {
        float s = 0.0f;
        for (int e = lane; e < E; e += 64) { float d = dirs[k * E + e]; s += d * d; }
        #pragma unroll
        for (int m = 32; m; m >>= 1) s += __shfl_xor(s, m);
        float nr = sqrtf(s);
        for (int e = lane; e < E; e += 64) u_n[k * E + e] = dirs[k * E + e] / nr;
    }

    // 1/s^2 and sum(log s)
    __shared__ float red[256];
    float lg = 0.0f;
    for (int e = tid; e < E; e += 256) {
        float s = stdev[e];
        invs2[e] = 1.0f / (s * s);
        lg += logf(s);
    }
    red[tid] = lg;
    __syncthreads();
    for (int off = 128; off; off >>= 1) {
        if (tid < off) red[tid] += red[tid + off];
        __syncthreads();
    }
    if (tid == 0) pf[PP_CNA] = -(0.5f * (float)E) * LOG2PI_F - red[0];

    // per-cluster constants
    if (tid < K) {
        float mu_ = mu[tid], sg_ = sigma[tid], la_ = lam[tid], as_ = astd[tid];
        float var = sg_ * sg_;
        float ak = mu_ + la_ * var;
        pf[PP_AK + tid] = ak;
        pf[PP_M2 + tid] = mu_ + ak;
        pf[PP_LT + tid] = 0.5f * la_;
        pf[PP_LC + tid] = logf(0.5f * la_);
        pf[PP_ISQ + tid] = 1.0f / (SQRT2_F * sg_);
        pf[PP_I2SA + tid] = 1.0f / (2.0f * as_ * as_);
        pf[PP_OC + tid] = -(0.5f * (float)(E - 1)) * LOG2PI_F - (float)(E - 1) * logf(as_);
    }

    // log_softmax of cluster weights
    if (tid == 0) {
        float m = -1e30f;
        for (int k = 0; k < K; ++k) m = fmaxf(m, w[k]);
        float s = 0.0f;
        for (int k = 0; k < K; ++k) s += expf(w[k] - m);
        float l = m + logf(s);
        for (int k = 0; k < K; ++k) pf[PP_LSM + k] = w[k] - l;
    }

    // exclusive prefix-sum of alt_counts -> per-variant read offsets
    __shared__ int sc[256];
    const int chunk = (B + 255) / 256;
    int s0 = 0;
    for (int i = 0; i < chunk; ++i) {
        int b = tid * chunk + i;
        if (b < B) s0 += counts[b];
    }
    sc[tid] = s0;
    __syncthreads();
    for (int off = 1; off < 256; off <<= 1) {
        int v = (tid >= off) ? sc[tid - off] : 0;
        __syncthreads();
        sc[tid] += v;
        __syncthreads();
    }
    int base = (tid == 0) ? 0 : sc[tid - 1];
    for (int i = 0; i < chunk; ++i) {
        int b = tid * chunk + i;
        if (b < B) { offs[b] = base; base += counts[b]; }
    }
}

// read -> variant map
__global__ __launch_bounds__(256) void k_seg(
    const int* __restrict__ offs, const int* __restrict__ counts,
    int* __restrict__ seg, int B, int R)
{
    int b = blockIdx.x * 256 + threadIdx.x;
    if (b >= B) return;
    int st = offs[b], c = counts[b];
    for (int i = 0; i < c; ++i) {
        int p = st + i;
        if (p < R) seg[p] = b;
    }
}

// ---------------------------------------------------------------------------
// Main fused kernel: 128 reads per block, 8x8 register tile per thread,
// Rot + Y in XOR-swizzled LDS (2 x 64 KB dynamic).
// ---------------------------------------------------------------------------
__global__ __launch_bounds__(256, 1) void k_main(
    const float* __restrict__ alt, const float* __restrict__ trans,
    const float* __restrict__ rot, const float* __restrict__ u_n,
    const float* __restrict__ invs2, const float* __restrict__ pf,
    const int* __restrict__ seg, float* __restrict__ accum)
{
    extern __shared__ float lds[];
    float* rot_s = lds;            // [128][128], f-quads XOR-swizzled by (row>>3)&7
    float* y_s   = lds + 16384;    // [128][128], same swizzle by read-row

    const int tid = threadIdx.x;
    const int rblk = blockIdx.x * 128;

    // stage Rot (transposed use: rows = output features e, cols = f)
    #pragma unroll
    for (int jj = 0; jj < 16; ++jj) {
        int f4 = tid + jj * 256;           // float4 index within 128x128
        int row = f4 >> 5;
        int fc = f4 & 31;
        float4 v = *(const float4*)(rot + ((size_t)row * 128 + fc * 4));
        int wc = fc ^ ((row >> 3) & 7);
        *(float4*)(rot_s + row * 128 + wc * 4) = v;
    }
    // stage Y = alt + t
    #pragma unroll
    for (int jj = 0; jj < 16; ++jj) {
        int f4 = tid + jj * 256;
        int row = f4 >> 5;
        int fc = f4 & 31;
        float4 a = *(const float4*)(alt + ((size_t)(rblk + row) * 128 + fc * 4));
        float4 t = *(const float4*)(trans + fc * 4);
        float4 v;
        v.x = a.x + t.x; v.y = a.y + t.y; v.z = a.z + t.z; v.w = a.w + t.w;
        int wc = fc ^ ((row >> 3) & 7);
        *(float4*)(y_s + row * 128 + wc * 4) = v;
    }
    __syncthreads();

    const int eg = tid & 15;          // e-group: 8 features
    const int rg = tid >> 4;          // r-group: 8 reads
    const int e0 = eg * 8;
    const int rr0 = rg * 8;

    float acc[8][8];
    #pragma unroll
    for (int i = 0; i < 8; ++i)
        #pragma unroll
        for (int j = 0; j < 8; ++j) acc[i][j] = 0.0f;

    #pragma unroll 2
    for (int fq = 0; fq < 32; ++fq) {
        const int wro = (fq ^ (eg & 7)) << 2;
        const int wyo = (fq ^ (rg & 7)) << 2;
        float4 rv[8], yv[8];
        #pragma unroll
        for (int i = 0; i < 8; ++i) rv[i] = *(const float4*)(rot_s + (e0 + i) * 128 + wro);
        #pragma unroll
        for (int j = 0; j < 8; ++j) yv[j] = *(const float4*)(y_s + (rr0 + j) * 128 + wyo);
        #pragma unroll
        for (int i = 0; i < 8; ++i) {
            #pragma unroll
            for (int j = 0; j < 8; ++j) {
                acc[i][j] = fmaf(rv[i].x, yv[j].x, acc[i][j]);
                acc[i][j] = fmaf(rv[i].y, yv[j].y, acc[i][j]);
                acc[i][j] = fmaf(rv[i].z, yv[j].z, acc[i][j]);
                acc[i][j] = fmaf(rv[i].w, yv[j].w, acc[i][j]);
            }
        }
    }

    // ---- phase 2: reductions straight from the accumulator tile ----
    int sg[8];
    #pragma unroll
    for (int j = 0; j < 8; ++j) sg[j] = seg[rblk + rr0 + j];

    float iv[8];
    {
        float4 a = *(const float4*)(invs2 + e0);
        float4 b = *(const float4*)(invs2 + e0 + 4);
        iv[0] = a.x; iv[1] = a.y; iv[2] = a.z; iv[3] = a.w;
        iv[4] = b.x; iv[5] = b.y; iv[6] = b.z; iv[7] = b.w;
    }

    float p1[8], p2[8];   // sum((x/s)^2), sum(x^2) partials over this thread's 8 e's
    #pragma unroll
    for (int j = 0; j < 8; ++j) {
        float s1 = 0.0f, s2 = 0.0f;
        #pragma unroll
        for (int i = 0; i < 8; ++i) {
            float x = acc[i][j];
            float x2 = x * x;
            s1 = fmaf(x2, iv[i], s1);
            s2 += x2;
        }
        p1[j] = s1; p2[j] = s2;
    }
    #pragma unroll
    for (int m = 1; m <= 8; m <<= 1) {
        #pragma unroll
        for (int j = 0; j < 8; ++j) {
            p1[j] += __shfl_xor(p1[j], m);
            p2[j] += __shfl_xor(p2[j], m);
        }
    }

    // 12 projection dots; lane eg==k keeps cluster k's dots
    float mydot[8];
    #pragma unroll
    for (int j = 0; j < 8; ++j) mydot[j] = 0.0f;

    for (int k = 0; k < 12; ++k) {
        float uv[8];
        {
            float4 a = *(const float4*)(u_n + (size_t)k * 128 + e0);
            float4 b = *(const float4*)(u_n + (size_t)k * 128 + e0 + 4);
            uv[0] = a.x; uv[1] = a.y; uv[2] = a.z; uv[3] = a.w;
            uv[4] = b.x; uv[5] = b.y; uv[6] = b.z; uv[7] = b.w;
        }
        float d[8];
        #pragma unroll
        for (int j = 0; j < 8; ++j) {
            float s = 0.0f;
            #pragma unroll
            for (int i = 0; i < 8; ++i) s = fmaf(acc[i][j], uv[i], s);
            d[j] = s;
        }
        #pragma unroll
        for (int m = 1; m <= 8; m <<= 1) {
            #pragma unroll
            for (int j = 0; j < 8; ++j) d[j] += __shfl_xor(d[j], m);
        }
        #pragma unroll
        for (int j = 0; j < 8; ++j)
            if (eg == k) mydot[j] = d[j];
    }

    // distribute EMG evaluation across eg lanes: lane eg<12 handles cluster eg,
    // lane eg==12 handles the nonartifact term.
    if (eg < 12) {
        const float ak   = pf[PP_AK + eg];
        const float m2   = pf[PP_M2 + eg];
        const float lt   = pf[PP_LT + eg];
        const float lc   = pf[PP_LC + eg];
        const float isq  = pf[PP_ISQ + eg];
        const float i2sa = pf[PP_I2SA + eg];
        const float oc   = pf[PP_OC + eg];
        #pragma unroll
        for (int j = 0; j < 8; ++j) {
            float dt = mydot[j];
            float orth2 = p2[j] - dt * dt;
            float z = (ak - dt) * isq;
            float art = oc - orth2 * i2sa
                      + lc + logerfc_f(z) + lt * (m2 - 2.0f * dt);
            atomicAdd(accum + (size_t)sg[j] * 16 + 1 + eg, art);
        }
    } else if (eg == 12) {
        const float cna = pf[PP_CNA];
        #pragma unroll
        for (int j = 0; j < 8; ++j)
            atomicAdd(accum + (size_t)sg[j] * 16, cna - 0.5f * p1[j]);
    }
}

// ---------------------------------------------------------------------------
// Finale: add log_softmax, logsumexp over clusters, capped logits, outputs
// ---------------------------------------------------------------------------
__global__ __launch_bounds__(256) void k_final(
    const float* __restrict__ accum, const float* __restrict__ pf,
    float* __restrict__ out, int B)
{
    int b = blockIdx.x * 256 + threadIdx.x;
    if (b >= B) return;
    const float* a = accum + (size_t)b * 16;
    float na = a[0];
    float art[12];
    float m = -1e30f;
    #pragma unroll
    for (int k = 0; k < 12; ++k) {
        art[k] = a[1 + k] + pf[PP_LSM + k];
        m = fmaxf(m, art[k]);
    }
    float s = 0.0f;
    #pragma unroll
    for (int k = 0; k < 12; ++k) s += expf(art[k] - m);
    float lse = m + logf(s);
    float logit = lse - na;
    out[b] = 20.0f * tanhf(logit / 20.0f);
    float* lk = out + B + (size_t)b * 13;
    lk[0] = na;
    #pragma unroll
    for (int k = 0; k < 12; ++k) lk[1 + k] = art[k];
}

// ---------------------------------------------------------------------------
extern "C" void kernel_launch(void* const* d_in, const int* in_sizes, int n_in,
                              void* d_out, int out_size, void* d_ws, size_t ws_size,
                              hipStream_t stream) {
    const float* alt    = (const float*)d_in[0];
    // d_in[1] ref_re: computed-but-unused in the reference; skipped.
    const float* trans  = (const float*)d_in[2];
    const float* rot    = (const float*)d_in[3];
    const float* stdev  = (const float*)d_in[4];
    const float* dirs   = (const float*)d_in[5];
    const float* mu     = (const float*)d_in[6];
    const float* sigma  = (const float*)d_in[7];
    const float* lam    = (const float*)d_in[8];
    const float* astd   = (const float*)d_in[9];
    const float* w      = (const float*)d_in[10];
    const int*   counts = (const int*)d_in[11];
    // d_in[12] ref_counts_b unused.

    const int E = in_sizes[2];          // 128
    const int R = in_sizes[0] / E;      // 65536
    const int K = in_sizes[6];          // 12
    const int B = in_sizes[11];         // 4096

    float* out = (float*)d_out;

    // workspace layout
    int*   seg   = (int*)d_ws;                       // [R]
    float* wsf   = (float*)d_ws + R;
    float* u_n   = wsf;                              // [K*E]
    float* invs2 = u_n + (size_t)K * E;              // [E]
    float* pf    = invs2 + E;                        // [PP_SIZE]
    int*   offs  = (int*)(pf + PP_SIZE);             // [B+1]
    size_t accoff = ((size_t)(K * E + E + PP_SIZE) + (size_t)B + 1 + 3) & ~(size_t)3;
    float* accum = wsf + accoff;                     // [B*16]

    hipMemsetAsync(accum, 0, (size_t)B * 16 * sizeof(float), stream);

    k_setup<<<1, 256, 0, stream>>>(trans, rot, stdev, dirs, mu, sigma, lam, astd,
                                   w, counts, u_n, invs2, pf, offs, B, R, E, K);
    k_seg<<<(B + 255) / 256, 256, 0, stream>>>(offs, counts, seg, B, R);

    hipFuncSetAttribute(reinterpret_cast<const void*>(k_main),
                        hipFuncAttributeMaxDynamicSharedMemorySize, 131072);
    k_main<<<R / 128, 256, 131072, stream>>>(alt, trans, rot, u_n, invs2, pf, seg, accum);

    k_final<<<(B + 255) / 256, 256, 0, stream>>>(accum, pf, out, B);
}

// Round 5
// 187.658 us; speedup vs baseline: 1.0247x; 1.0247x over previous
//
#include <hip/hip_runtime.h>
#include <hip/hip_bf16.h>
#include <math.h>

// ---------------------------------------------------------------------------
// FeatureClustering via split-bf16 MFMA.
//   Y = alt + t  (fp32) -> split into 3 bf16 planes (hi/mid/lo, err <= 2^-25)
//   x = Y @ Rot^T  via 6 MFMA products (hh,hm,mh,mm,hl,lh) -> fp32-grade
//   dot_rk = Y @ v_k, v_k = Rot^T u_k (3-plane split, 6 products)
//   orth2 = ||x||^2 - dot^2 ;  EMG + orth ll ; ragged segment sums -> logits
// 3 dispatches total: k_pre (10 blocks) -> k_main (R/64) -> k_final.
// ---------------------------------------------------------------------------

#define LOG2PI_F 1.8378770664093453f
#define SQRTPI_F 1.7724538509055159f
#define SQRT2_F  1.4142135623730951f

#define PP_AK   0     // mu + lambda*sigma^2
#define PP_M2   12    // 2*mu + lambda*sigma^2
#define PP_LT   24    // lambda/2
#define PP_LC   36    // log(lambda/2)
#define PP_ISQ  48    // 1/(sqrt(2)*sigma)
#define PP_I2SA 60    // 1/(2*artifact_stdev^2)
#define PP_OC   72    // orth const
#define PP_LSM  84    // log_softmax(weights)
#define PP_CNA  96    // nonartifact const
#define PP_SIZE 112

typedef __attribute__((ext_vector_type(8)))  short  bfrag8;   // 8 bf16
typedef __attribute__((ext_vector_type(16))) float  f32x16;
typedef __attribute__((ext_vector_type(4)))  float  f32x4;

#define MFMA32(a,b,c) __builtin_amdgcn_mfma_f32_32x32x16_bf16((a),(b),(c),0,0,0)
#define MFMA16(a,b,c) __builtin_amdgcn_mfma_f32_16x16x32_bf16((a),(b),(c),0,0,0)

__device__ __forceinline__ unsigned short f2bf(float x) {
    union { float f; unsigned u; } v; v.f = x;
    unsigned r = v.u + 0x7FFFu + ((v.u >> 16) & 1u);
    return (unsigned short)(r >> 16);
}
__device__ __forceinline__ float bf2f(unsigned short b) {
    union { float f; unsigned u; } v; v.u = ((unsigned)b) << 16; return v.f;
}

__device__ __forceinline__ float logerfc_f(float z) {
    if (z > 5.0f) {
        float z2 = z * z;
        float rz2 = 1.0f / z2;
        float corr = rz2 * (-0.5f + rz2 * (0.75f - 1.875f * rz2));
        return -z2 - logf(z * SQRTPI_F) + log1pf(corr);
    }
    return logf(erfcf(z));
}

// ---------------------------------------------------------------------------
// k_pre, 10 blocks:
//  blocks 0-7: split Rot into 3 bf16 planes, chunk-major:
//      wsB[(p*16384) + (ch*128 + e)*8 + j], f = ch*8+j, value = Rot[e][f]
//  block 8:    v_n = (Rot^T dirs_n)/||dirs_n||, 3-plane split:
//      wsV[(p*2048) + (ch*16 + n)*8 + j]   (rows n>=12 zero)
//  block 9:    invs2, pf consts, log_softmax, seg map, zero accum
// ---------------------------------------------------------------------------
__global__ __launch_bounds__(256) void k_pre(
    const float* __restrict__ rot, const float* __restrict__ dirs,
    const float* __restrict__ stdev, const float* __restrict__ mu,
    const float* __restrict__ sigma, const float* __restrict__ lam,
    const float* __restrict__ astd, const float* __restrict__ w,
    const int* __restrict__ counts,
    unsigned short* __restrict__ wsB, unsigned short* __restrict__ wsV,
    float* __restrict__ invs2, float* __restrict__ pf,
    int* __restrict__ seg, float* __restrict__ accum,
    int B, int R, int E, int K)
{
    const int tid = threadIdx.x;

    if (blockIdx.x < 8) {
        // ---- split Rot ----
        int gid = blockIdx.x * 256 + tid;      // [0, 2048)
        int e = gid >> 4, ch = gid & 15;
        const float* src = rot + e * 128 + ch * 8;
        #pragma unroll
        for (int j = 0; j < 8; ++j) {
            float x = src[j];
            unsigned short hb = f2bf(x);  float r1 = x - bf2f(hb);
            unsigned short mb = f2bf(r1); float r2 = r1 - bf2f(mb);
            unsigned short lb = f2bf(r2);
            size_t idx = ((size_t)ch * 128 + e) * 8 + j;
            wsB[idx] = hb;
            wsB[idx + 16384] = mb;       // plane stride = 16*128*8
            wsB[idx + 32768] = lb;
        }
    } else if (blockIdx.x == 8) {
        // ---- v_n = Rot^T u_n, inline normalization ----
        __shared__ float sinv[16];
        const int lane = tid & 63;
        const int wv = tid >> 6;
        for (int k = wv; k < 12; k += 4) {
            float s = 0.0f;
            for (int e = lane; e < 128; e += 64) { float d = dirs[k * 128 + e]; s += d * d; }
            #pragma unroll
            for (int m = 32; m; m >>= 1) s += __shfl_xor(s, m);
            if (lane == 0) sinv[k] = 1.0f / sqrtf(s);
        }
        __syncthreads();
        int n = tid >> 4, ch = tid & 15;
        float v[8];
        #pragma unroll
        for (int j = 0; j < 8; ++j) v[j] = 0.0f;
        if (n < 12) {
            for (int e = 0; e < 128; ++e) {
                float de = dirs[n * 128 + e];
                const float* rr = rot + e * 128 + ch * 8;
                #pragma unroll
                for (int j = 0; j < 8; ++j) v[j] = fmaf(rr[j], de, v[j]);
            }
            float inv = sinv[n];
            #pragma unroll
            for (int j = 0; j < 8; ++j) v[j] *= inv;
        }
        #pragma unroll
        for (int j = 0; j < 8; ++j) {
            unsigned short hb = f2bf(v[j]);  float r1 = v[j] - bf2f(hb);
            unsigned short mb = f2bf(r1);    float r2 = r1 - bf2f(mb);
            unsigned short lb = f2bf(r2);
            size_t idx = ((size_t)ch * 16 + n) * 8 + j;
            wsV[idx] = hb;
            wsV[idx + 2048] = mb;        // plane stride = 16*16*8
            wsV[idx + 4096] = lb;
        }
    } else {
        // ---- setup block ----
        __shared__ float red[256];
        float lg = 0.0f;
        for (int e = tid; e < E; e += 256) {
            float s = stdev[e];
            invs2[e] = 1.0f / (s * s);
            lg += logf(s);
        }
        red[tid] = lg;
        __syncthreads();
        for (int off = 128; off; off >>= 1) {
            if (tid < off) red[tid] += red[tid + off];
            __syncthreads();
        }
        if (tid == 0) pf[PP_CNA] = -(0.5f * (float)E) * LOG2PI_F - red[0];

        if (tid < K) {
            float mu_ = mu[tid], sg_ = sigma[tid], la_ = lam[tid], as_ = astd[tid];
            float var = sg_ * sg_;
            float ak = mu_ + la_ * var;
            pf[PP_AK + tid] = ak;
            pf[PP_M2 + tid] = mu_ + ak;
            pf[PP_LT + tid] = 0.5f * la_;
            pf[PP_LC + tid] = logf(0.5f * la_);
            pf[PP_ISQ + tid] = 1.0f / (SQRT2_F * sg_);
            pf[PP_I2SA + tid] = 1.0f / (2.0f * as_ * as_);
            pf[PP_OC + tid] = -(0.5f * (float)(E - 1)) * LOG2PI_F - (float)(E - 1) * logf(as_);
        }

        if (tid == 0) {
            float m = -1e30f;
            for (int k = 0; k < K; ++k) m = fmaxf(m, w[k]);
            float s = 0.0f;
            for (int k = 0; k < K; ++k) s += expf(w[k] - m);
            float l = m + logf(s);
            for (int k = 0; k < K; ++k) pf[PP_LSM + k] = w[k] - l;
        }

        // exclusive scan of counts -> seg map
        __shared__ int sc[256];
        const int chunk = (B + 255) / 256;
        int s0 = 0;
        for (int i = 0; i < chunk; ++i) {
            int b = tid * chunk + i;
            if (b < B) s0 += counts[b];
        }
        sc[tid] = s0;
        __syncthreads();
        for (int off = 1; off < 256; off <<= 1) {
            int v = (tid >= off) ? sc[tid - off] : 0;
            __syncthreads();
            sc[tid] += v;
            __syncthreads();
        }
        int base = (tid == 0) ? 0 : sc[tid - 1];
        for (int i = 0; i < chunk; ++i) {
            int b = tid * chunk + i;
            if (b < B) {
                int c = counts[b];
                for (int j = 0; j < c; ++j) { int p = base + j; if (p < R) seg[p] = b; }
                base += c;
            }
        }

        // zero the accumulator buffer
        float4 z4; z4.x = z4.y = z4.z = z4.w = 0.0f;
        float4* ac4 = (float4*)accum;
        const int n4 = B * 16 / 4;
        for (int i = tid; i < n4; i += 256) ac4[i] = z4;
    }
}

// ---------------------------------------------------------------------------
// k_main: 64 reads/block, 256 threads (4 waves).
// LDS 52KB: A planes 3x[64][16 chunks][16B] (48KB, XOR-swizzled) + dot_s 4KB.
// Wave w: mt = w&1 (32 rows), np = w>>1 (64 e-cols); acc = 2 x f32x16.
// B fragments stream directly from global (L2-resident, pre-split).
// ---------------------------------------------------------------------------
__global__ __launch_bounds__(256, 2) void k_main(
    const float* __restrict__ alt, const float* __restrict__ trans,
    const unsigned short* __restrict__ wsB, const unsigned short* __restrict__ wsV,
    const float* __restrict__ invs2, const float* __restrict__ pf,
    const int* __restrict__ seg, float* __restrict__ accum, int B)
{
    extern __shared__ char lds[];
    const int tid = threadIdx.x;
    const int lane = tid & 63;
    const int w = tid >> 6;
    const int rblk = blockIdx.x * 64;

    // ---- stage A: y = alt + trans, 3-way split, swizzled LDS ----
    {
        const int row = tid >> 2;
        const int a = tid & 3;
        const float* arow = alt + (size_t)(rblk + row) * 128;
        #pragma unroll
        for (int i = 0; i < 4; ++i) {
            int pc = a + 4 * ((i + row) & 3);   // physical chunk (conflict-spread)
            int c  = pc ^ (row & 15);           // logical chunk
            float4 x0 = *(const float4*)(arow + c * 8);
            float4 x1 = *(const float4*)(arow + c * 8 + 4);
            float4 t0 = *(const float4*)(trans + c * 8);
            float4 t1 = *(const float4*)(trans + c * 8 + 4);
            float y[8] = {x0.x + t0.x, x0.y + t0.y, x0.z + t0.z, x0.w + t0.w,
                          x1.x + t1.x, x1.y + t1.y, x1.z + t1.z, x1.w + t1.w};
            union { unsigned short u[8]; bfrag8 v; } uh, um, ul;
            #pragma unroll
            for (int j = 0; j < 8; ++j) {
                unsigned short hb = f2bf(y[j]); float r1 = y[j] - bf2f(hb);
                unsigned short mb = f2bf(r1);  float r2 = r1 - bf2f(mb);
                unsigned short lb = f2bf(r2);
                uh.u[j] = hb; um.u[j] = mb; ul.u[j] = lb;
            }
            int base = row * 256 + pc * 16;
            *(bfrag8*)(lds + base)         = uh.v;
            *(bfrag8*)(lds + 16384 + base) = um.v;
            *(bfrag8*)(lds + 32768 + base) = ul.v;
        }
    }
    __syncthreads();

    // ---- V-GEMM (16x16x32): wave w owns rows 16w..16w+15; dots = Y @ V ----
    f32x4 dacc;
    #pragma unroll
    for (int i = 0; i < 4; ++i) dacc[i] = 0.0f;
    {
        const int rowA = 16 * w + (lane & 15);
        const int g = lane >> 4;
        const int n = lane & 15;
        #pragma unroll
        for (int kst = 0; kst < 4; ++kst) {
            int ch = kst * 4 + g;
            int pc = ch ^ (rowA & 15);
            int base = rowA * 256 + pc * 16;
            bfrag8 ah = *(const bfrag8*)(lds + base);
            bfrag8 am = *(const bfrag8*)(lds + 16384 + base);
            bfrag8 al = *(const bfrag8*)(lds + 32768 + base);
            const unsigned short* vp = wsV + ((size_t)ch * 16 + n) * 8;
            bfrag8 vh = *(const bfrag8*)(vp);
            bfrag8 vm = *(const bfrag8*)(vp + 2048);
            bfrag8 vl = *(const bfrag8*)(vp + 4096);
            dacc = MFMA16(al, vh, dacc);
            dacc = MFMA16(am, vm, dacc);
            dacc = MFMA16(ah, vl, dacc);
            dacc = MFMA16(am, vh, dacc);
            dacc = MFMA16(ah, vm, dacc);
            dacc = MFMA16(ah, vh, dacc);
        }
    }

    // ---- main GEMM (32x32x16): x = Y @ Rot^T, 6 split products ----
    f32x16 acc0, acc1;
    #pragma unroll
    for (int i = 0; i < 16; ++i) { acc0[i] = 0.0f; acc1[i] = 0.0f; }
    const int mt = w & 1;
    const int np = w >> 1;
    {
        const int rowA = 32 * mt + (lane & 31);
        const int g = lane >> 5;
        const int e0 = 64 * np + (lane & 31);
        #pragma unroll 2
        for (int kst = 0; kst < 8; ++kst) {
            int ch = kst * 2 + g;
            int pc = ch ^ (rowA & 15);
            int base = rowA * 256 + pc * 16;
            bfrag8 ah = *(const bfrag8*)(lds + base);
            bfrag8 am = *(const bfrag8*)(lds + 16384 + base);
            bfrag8 al = *(const bfrag8*)(lds + 32768 + base);
            const unsigned short* b0 = wsB + ((size_t)ch * 128 + e0) * 8;
            const unsigned short* b1 = b0 + 32 * 8;
            bfrag8 bh0 = *(const bfrag8*)(b0);
            bfrag8 bm0 = *(const bfrag8*)(b0 + 16384);
            bfrag8 bl0 = *(const bfrag8*)(b0 + 32768);
            bfrag8 bh1 = *(const bfrag8*)(b1);
            bfrag8 bm1 = *(const bfrag8*)(b1 + 16384);
            bfrag8 bl1 = *(const bfrag8*)(b1 + 32768);
            acc0 = MFMA32(al, bh0, acc0);  acc1 = MFMA32(al, bh1, acc1);
            acc0 = MFMA32(am, bm0, acc0);  acc1 = MFMA32(am, bm1, acc1);
            acc0 = MFMA32(ah, bl0, acc0);  acc1 = MFMA32(ah, bl1, acc1);
            acc0 = MFMA32(am, bh0, acc0);  acc1 = MFMA32(am, bh1, acc1);
            acc0 = MFMA32(ah, bm0, acc0);  acc1 = MFMA32(ah, bm1, acc1);
            acc0 = MFMA32(ah, bh0, acc0);  acc1 = MFMA32(ah, bh1, acc1);
        }
    }
    __syncthreads();   // all waves done reading A planes

    // ---- write x (swizzled) into A region; dots into dot_s ----
    float* xs = (float*)lds;                   // [64][128] swizzled
    float* dots = (float*)(lds + 49152);       // [64][16]
    #pragma unroll
    for (int r = 0; r < 4; ++r)
        dots[(16 * w + (lane >> 4) * 4 + r) * 16 + (lane & 15)] = dacc[r];
    {
        const int eb = 64 * np + (lane & 31);
        #pragma unroll
        for (int r = 0; r < 16; ++r) {
            int m = 32 * mt + (r & 3) + 8 * (r >> 2) + 4 * (lane >> 5);
            int x0i = eb ^ ((m & 7) << 2);
            int x1i = (eb + 32) ^ ((m & 7) << 2);
            xs[m * 128 + x0i] = acc0[r];
            xs[m * 128 + x1i] = acc1[r];
        }
    }
    __syncthreads();

    // ---- phase 2: p1/p2 reductions + EMG + segment atomics ----
    {
        const int m = tid >> 2;
        const int q = tid & 3;
        float p1 = 0.0f, p2 = 0.0f;
        #pragma unroll
        for (int i = 0; i < 8; ++i) {
            int eq = q * 8 + i;                 // logical float4-group
            int peq = eq ^ (m & 7);             // physical float4-group
            // physical float 4*peq+d holds LOGICAL feature 4*eq+d,
            // so weights are indexed by eq (logical), x by peq (physical).
            float4 x4 = *(const float4*)(xs + m * 128 + peq * 4);
            float4 w4 = *(const float4*)(invs2 + eq * 4);
            float s2 = x4.x * x4.x + x4.y * x4.y + x4.z * x4.z + x4.w * x4.w;
            p2 += s2;
            p1 += x4.x * x4.x * w4.x + x4.y * x4.y * w4.y
                + x4.z * x4.z * w4.z + x4.w * x4.w * w4.w;
        }
        p1 += __shfl_xor(p1, 1); p1 += __shfl_xor(p1, 2);
        p2 += __shfl_xor(p2, 1); p2 += __shfl_xor(p2, 2);
        int sv = seg[rblk + m];
        sv = (sv < 0) ? 0 : ((sv >= B) ? B - 1 : sv);
        #pragma unroll
        for (int j = 0; j < 3; ++j) {
            int k = q + 4 * j;
            float dt = dots[m * 16 + k];
            float orth2 = p2 - dt * dt;
            float z = (pf[PP_AK + k] - dt) * pf[PP_ISQ + k];
            float art = pf[PP_OC + k] - orth2 * pf[PP_I2SA + k]
                      + pf[PP_LC + k] + logerfc_f(z)
                      + pf[PP_LT + k] * (pf[PP_M2 + k] - 2.0f * dt);
            atomicAdd(accum + (size_t)sv * 16 + 1 + k, art);
        }
        if (q == 0) atomicAdd(accum + (size_t)sv * 16, pf[PP_CNA] - 0.5f * p1);
    }
}

// ---------------------------------------------------------------------------
__global__ __launch_bounds__(256) void k_final(
    const float* __restrict__ accum, const float* __restrict__ pf,
    float* __restrict__ out, int B)
{
    int b = blockIdx.x * 256 + threadIdx.x;
    if (b >= B) return;
    const float* a = accum + (size_t)b * 16;
    float na = a[0];
    float art[12];
    float m = -1e30f;
    #pragma unroll
    for (int k = 0; k < 12; ++k) {
        art[k] = a[1 + k] + pf[PP_LSM + k];
        m = fmaxf(m, art[k]);
    }
    float s = 0.0f;
    #pragma unroll
    for (int k = 0; k < 12; ++k) s += expf(art[k] - m);
    float lse = m + logf(s);
    float logit = lse - na;
    out[b] = 20.0f * tanhf(logit / 20.0f);
    float* lk = out + B + (size_t)b * 13;
    lk[0] = na;
    #pragma unroll
    for (int k = 0; k < 12; ++k) lk[1 + k] = art[k];
}

// ---------------------------------------------------------------------------
extern "C" void kernel_launch(void* const* d_in, const int* in_sizes, int n_in,
                              void* d_out, int out_size, void* d_ws, size_t ws_size,
                              hipStream_t stream) {
    const float* alt    = (const float*)d_in[0];
    // d_in[1] ref_re unused by reference output
    const float* trans  = (const float*)d_in[2];
    const float* rot    = (const float*)d_in[3];
    const float* stdev  = (const float*)d_in[4];
    const float* dirs   = (const float*)d_in[5];
    const float* mu     = (const float*)d_in[6];
    const float* sigma  = (const float*)d_in[7];
    const float* lam    = (const float*)d_in[8];
    const float* astd   = (const float*)d_in[9];
    const float* w      = (const float*)d_in[10];
    const int*   counts = (const int*)d_in[11];
    // d_in[12] ref_counts_b unused

    const int E = in_sizes[2];          // 128
    const int R = in_sizes[0] / E;      // 65536
    const int K = in_sizes[6];          // 12
    const int B = in_sizes[11];         // 4096

    float* out = (float*)d_out;

    // workspace layout (all 16B aligned)
    int*            seg   = (int*)d_ws;                           // R ints
    float*          invs2 = (float*)(seg + R);                    // E
    float*          pf    = invs2 + E;                            // PP_SIZE
    unsigned short* wsB   = (unsigned short*)(pf + PP_SIZE);      // 3*16*128*8
    unsigned short* wsV   = wsB + 3 * 16 * 128 * 8;               // 3*16*16*8
    float*          accum = (float*)(wsV + 3 * 16 * 16 * 8);      // B*16

    k_pre<<<10, 256, 0, stream>>>(rot, dirs, stdev, mu, sigma, lam, astd, w,
                                  counts, wsB, wsV, invs2, pf, seg, accum,
                                  B, R, E, K);
    k_main<<<R / 64, 256, 53248, stream>>>(alt, trans, wsB, wsV, invs2, pf,
                                           seg, accum, B);
    k_final<<<(B + 255) / 256, 256, 0, stream>>>(accum, pf, out, B);
}

// Round 6
// 146.805 us; speedup vs baseline: 1.3098x; 1.2783x over previous
//
#include <hip/hip_runtime.h>
#include <hip/hip_bf16.h>
#include <math.h>

// ---------------------------------------------------------------------------
// FeatureClustering via split-bf16 MFMA.
//   Y = alt + t  (fp32) -> split into 3 bf16 planes (hi/mid/lo, err <= 2^-25)
//   x = Y @ Rot^T  via 6 MFMA products (hh,hm,mh,mm,hl,lh) -> fp32-grade
//   dot_rk = Y @ v_k, v_k = Rot^T u_k (3-plane split, 6 products)
//   orth2 = ||x||^2 - dot^2 ;  EMG + orth ll ; ragged segment sums -> logits
// 4 dispatches: k_pre (25 blocks) -> k_seg (16) -> k_main (R/64) -> k_final.
// ---------------------------------------------------------------------------

#define LOG2PI_F 1.8378770664093453f
#define SQRTPI_F 1.7724538509055159f
#define SQRT2_F  1.4142135623730951f

#define PP_AK   0     // mu + lambda*sigma^2
#define PP_M2   12    // 2*mu + lambda*sigma^2
#define PP_LT   24    // lambda/2
#define PP_LC   36    // log(lambda/2)
#define PP_ISQ  48    // 1/(sqrt(2)*sigma)
#define PP_I2SA 60    // 1/(2*artifact_stdev^2)
#define PP_OC   72    // orth const
#define PP_LSM  84    // log_softmax(weights)
#define PP_CNA  96    // nonartifact const
#define PP_SIZE 112

typedef __attribute__((ext_vector_type(8)))  short  bfrag8;   // 8 bf16
typedef __attribute__((ext_vector_type(16))) float  f32x16;
typedef __attribute__((ext_vector_type(4)))  float  f32x4;

#define MFMA32(a,b,c) __builtin_amdgcn_mfma_f32_32x32x16_bf16((a),(b),(c),0,0,0)
#define MFMA16(a,b,c) __builtin_amdgcn_mfma_f32_16x16x32_bf16((a),(b),(c),0,0,0)

__device__ __forceinline__ unsigned short f2bf(float x) {
    union { float f; unsigned u; } v; v.f = x;
    unsigned r = v.u + 0x7FFFu + ((v.u >> 16) & 1u);
    return (unsigned short)(r >> 16);
}
__device__ __forceinline__ float bf2f(unsigned short b) {
    union { float f; unsigned u; } v; v.u = ((unsigned)b) << 16; return v.f;
}

__device__ __forceinline__ float logerfc_f(float z) {
    if (z > 5.0f) {
        float z2 = z * z;
        float rz2 = 1.0f / z2;
        float corr = rz2 * (-0.5f + rz2 * (0.75f - 1.875f * rz2));
        return -z2 - logf(z * SQRTPI_F) + log1pf(corr);
    }
    return logf(erfcf(z));
}

// ---------------------------------------------------------------------------
// k_pre, 25 blocks:
//  blocks 0-7 : split Rot into 3 bf16 planes, chunk-major
//  blocks 8-19: v_n = (Rot^T dirs_n)/||dirs_n|| for n = bid-8, e-parallel
//  block 20   : invs2, pf consts, log_softmax, scan -> offs[B+1]
//  blocks 21-24: zero accum (coalesced float4)
// ---------------------------------------------------------------------------
__global__ __launch_bounds__(256) void k_pre(
    const float* __restrict__ rot, const float* __restrict__ dirs,
    const float* __restrict__ stdev, const float* __restrict__ mu,
    const float* __restrict__ sigma, const float* __restrict__ lam,
    const float* __restrict__ astd, const float* __restrict__ w,
    const int* __restrict__ counts,
    unsigned short* __restrict__ wsB, unsigned short* __restrict__ wsV,
    float* __restrict__ invs2, float* __restrict__ pf,
    int* __restrict__ offs, float* __restrict__ accum,
    int B, int R, int E, int K)
{
    const int tid = threadIdx.x;
    const int bid = blockIdx.x;

    if (bid < 8) {
        // ---- split Rot ----
        int gid = bid * 256 + tid;             // [0, 2048)
        int e = gid >> 4, ch = gid & 15;
        const float* src = rot + e * 128 + ch * 8;
        #pragma unroll
        for (int j = 0; j < 8; ++j) {
            float x = src[j];
            unsigned short hb = f2bf(x);  float r1 = x - bf2f(hb);
            unsigned short mb = f2bf(r1); float r2 = r1 - bf2f(mb);
            unsigned short lb = f2bf(r2);
            size_t idx = ((size_t)ch * 128 + e) * 8 + j;
            wsB[idx] = hb;
            wsB[idx + 16384] = mb;       // plane stride = 16*128*8
            wsB[idx + 32768] = lb;
        }
    } else if (bid < 20) {
        // ---- v_n for cluster n, parallel over e with LDS reduce ----
        const int n = bid - 8;
        __shared__ float vp[256];
        __shared__ float sred[4];
        __shared__ float snorm;
        // ||dirs_n||: threads 0-127 contribute
        float d = (tid < 128) ? dirs[n * 128 + tid] : 0.0f;
        float s = d * d;
        #pragma unroll
        for (int m = 32; m; m >>= 1) s += __shfl_xor(s, m);
        if ((tid & 63) == 0) sred[tid >> 6] = s;
        __syncthreads();
        if (tid == 0) snorm = rsqrtf(sred[0] + sred[1] + sred[2] + sred[3]);
        // partial dot: thread (f = tid&127, half h = tid>>7) over 64 e's
        const int f = tid & 127, h = tid >> 7;
        float acc = 0.0f;
        #pragma unroll 8
        for (int e = h * 64; e < h * 64 + 64; ++e)
            acc = fmaf(rot[e * 128 + f], dirs[n * 128 + e], acc);
        vp[tid] = acc;
        __syncthreads();
        if (tid < 128) {
            float v = (vp[tid] + vp[tid + 128]) * snorm;
            unsigned short hb = f2bf(v);  float r1 = v - bf2f(hb);
            unsigned short mb = f2bf(r1); float r2 = r1 - bf2f(mb);
            unsigned short lb = f2bf(r2);
            size_t idx = ((size_t)(f >> 3) * 16 + n) * 8 + (f & 7);
            wsV[idx] = hb;
            wsV[idx + 2048] = mb;        // plane stride = 16*16*8
            wsV[idx + 4096] = lb;
        }
    } else if (bid == 20) {
        // ---- consts + scan -> offs ----
        __shared__ float red[256];
        float lg = 0.0f;
        for (int e = tid; e < E; e += 256) {
            float s = stdev[e];
            invs2[e] = 1.0f / (s * s);
            lg += logf(s);
        }
        red[tid] = lg;
        __syncthreads();
        for (int off = 128; off; off >>= 1) {
            if (tid < off) red[tid] += red[tid + off];
            __syncthreads();
        }
        if (tid == 0) pf[PP_CNA] = -(0.5f * (float)E) * LOG2PI_F - red[0];

        if (tid < K) {
            float mu_ = mu[tid], sg_ = sigma[tid], la_ = lam[tid], as_ = astd[tid];
            float var = sg_ * sg_;
            float ak = mu_ + la_ * var;
            pf[PP_AK + tid] = ak;
            pf[PP_M2 + tid] = mu_ + ak;
            pf[PP_LT + tid] = 0.5f * la_;
            pf[PP_LC + tid] = logf(0.5f * la_);
            pf[PP_ISQ + tid] = 1.0f / (SQRT2_F * sg_);
            pf[PP_I2SA + tid] = 1.0f / (2.0f * as_ * as_);
            pf[PP_OC + tid] = -(0.5f * (float)(E - 1)) * LOG2PI_F - (float)(E - 1) * logf(as_);
        }

        if (tid == 0) {
            float m = -1e30f;
            for (int k = 0; k < K; ++k) m = fmaxf(m, w[k]);
            float s = 0.0f;
            for (int k = 0; k < K; ++k) s += expf(w[k] - m);
            float l = m + logf(s);
            for (int k = 0; k < K; ++k) pf[PP_LSM + k] = w[k] - l;
        }

        // exclusive scan of counts -> offs[0..B], offs[B] = total
        __shared__ int sc[256];
        const int chunk = (B + 255) / 256;
        int s0 = 0;
        for (int i = 0; i < chunk; ++i) {
            int b = tid * chunk + i;
            if (b < B) s0 += counts[b];
        }
        sc[tid] = s0;
        __syncthreads();
        for (int off = 1; off < 256; off <<= 1) {
            int v = (tid >= off) ? sc[tid - off] : 0;
            __syncthreads();
            sc[tid] += v;
            __syncthreads();
        }
        int base = (tid == 0) ? 0 : sc[tid - 1];
        for (int i = 0; i < chunk; ++i) {
            int b = tid * chunk + i;
            if (b < B) { offs[b] = base; base += counts[b]; }
        }
        if (tid == 255) offs[B] = sc[255];
    } else {
        // ---- zero accum: 4 blocks x 256 threads x 16 float4 ----
        const int blk = bid - 21;
        float4 z4; z4.x = z4.y = z4.z = z4.w = 0.0f;
        float4* ac4 = (float4*)accum + (size_t)blk * 4096;
        const int lim = B * 16 / 4 - blk * 4096;
        #pragma unroll
        for (int i = 0; i < 16; ++i) {
            int idx = tid + i * 256;
            if (idx < lim && idx < 4096) ac4[idx] = z4;
        }
    }
}

// ---------------------------------------------------------------------------
// seg fill: one thread per variant, writes its read range
// ---------------------------------------------------------------------------
__global__ __launch_bounds__(256) void k_seg(
    const int* __restrict__ offs, const int* __restrict__ counts,
    int* __restrict__ seg, int B, int R)
{
    int b = blockIdx.x * 256 + threadIdx.x;
    if (b >= B) return;
    int st = offs[b], c = counts[b];
    for (int i = 0; i < c; ++i) {
        int p = st + i;
        if (p < R) seg[p] = b;
    }
}

// ---------------------------------------------------------------------------
// k_main: 64 reads/block, 256 threads (4 waves).
// LDS 52KB: A planes 3x[64][16 chunks][16B] (48KB, XOR-swizzled) + dot_s 4KB.
// Wave w: mt = w&1 (32 rows), np = w>>1 (64 e-cols); acc = 2 x f32x16.
// B fragments stream directly from global (L2-resident, pre-split).
// Epilogue: wave-level reduction over the 16 rows of each (uniform) variant
// before atomics: 52 atomics/block instead of ~900.
// ---------------------------------------------------------------------------
__global__ __launch_bounds__(256, 2) void k_main(
    const float* __restrict__ alt, const float* __restrict__ trans,
    const unsigned short* __restrict__ wsB, const unsigned short* __restrict__ wsV,
    const float* __restrict__ invs2, const float* __restrict__ pf,
    const int* __restrict__ seg, float* __restrict__ accum, int B)
{
    extern __shared__ char lds[];
    const int tid = threadIdx.x;
    const int lane = tid & 63;
    const int w = tid >> 6;
    const int rblk = blockIdx.x * 64;

    // ---- stage A: y = alt + trans, 3-way split, swizzled LDS ----
    {
        const int row = tid >> 2;
        const int a = tid & 3;
        const float* arow = alt + (size_t)(rblk + row) * 128;
        #pragma unroll
        for (int i = 0; i < 4; ++i) {
            int pc = a + 4 * ((i + row) & 3);   // physical chunk (conflict-spread)
            int c  = pc ^ (row & 15);           // logical chunk
            float4 x0 = *(const float4*)(arow + c * 8);
            float4 x1 = *(const float4*)(arow + c * 8 + 4);
            float4 t0 = *(const float4*)(trans + c * 8);
            float4 t1 = *(const float4*)(trans + c * 8 + 4);
            float y[8] = {x0.x + t0.x, x0.y + t0.y, x0.z + t0.z, x0.w + t0.w,
                          x1.x + t1.x, x1.y + t1.y, x1.z + t1.z, x1.w + t1.w};
            union { unsigned short u[8]; bfrag8 v; } uh, um, ul;
            #pragma unroll
            for (int j = 0; j < 8; ++j) {
                unsigned short hb = f2bf(y[j]); float r1 = y[j] - bf2f(hb);
                unsigned short mb = f2bf(r1);  float r2 = r1 - bf2f(mb);
                unsigned short lb = f2bf(r2);
                uh.u[j] = hb; um.u[j] = mb; ul.u[j] = lb;
            }
            int base = row * 256 + pc * 16;
            *(bfrag8*)(lds + base)         = uh.v;
            *(bfrag8*)(lds + 16384 + base) = um.v;
            *(bfrag8*)(lds + 32768 + base) = ul.v;
        }
    }
    __syncthreads();

    // ---- V-GEMM (16x16x32): wave w owns rows 16w..16w+15; dots = Y @ V ----
    f32x4 dacc;
    #pragma unroll
    for (int i = 0; i < 4; ++i) dacc[i] = 0.0f;
    {
        const int rowA = 16 * w + (lane & 15);
        const int g = lane >> 4;
        const int n = lane & 15;
        #pragma unroll
        for (int kst = 0; kst < 4; ++kst) {
            int ch = kst * 4 + g;
            int pc = ch ^ (rowA & 15);
            int base = rowA * 256 + pc * 16;
            bfrag8 ah = *(const bfrag8*)(lds + base);
            bfrag8 am = *(const bfrag8*)(lds + 16384 + base);
            bfrag8 al = *(const bfrag8*)(lds + 32768 + base);
            const unsigned short* vp = wsV + ((size_t)ch * 16 + n) * 8;
            bfrag8 vh = *(const bfrag8*)(vp);
            bfrag8 vm = *(const bfrag8*)(vp + 2048);
            bfrag8 vl = *(const bfrag8*)(vp + 4096);
            dacc = MFMA16(al, vh, dacc);
            dacc = MFMA16(am, vm, dacc);
            dacc = MFMA16(ah, vl, dacc);
            dacc = MFMA16(am, vh, dacc);
            dacc = MFMA16(ah, vm, dacc);
            dacc = MFMA16(ah, vh, dacc);
        }
    }

    // ---- main GEMM (32x32x16): x = Y @ Rot^T, 6 split products ----
    f32x16 acc0, acc1;
    #pragma unroll
    for (int i = 0; i < 16; ++i) { acc0[i] = 0.0f; acc1[i] = 0.0f; }
    const int mt = w & 1;
    const int np = w >> 1;
    {
        const int rowA = 32 * mt + (lane & 31);
        const int g = lane >> 5;
        const int e0 = 64 * np + (lane & 31);
        #pragma unroll 2
        for (int kst = 0; kst < 8; ++kst) {
            int ch = kst * 2 + g;
            int pc = ch ^ (rowA & 15);
            int base = rowA * 256 + pc * 16;
            bfrag8 ah = *(const bfrag8*)(lds + base);
            bfrag8 am = *(const bfrag8*)(lds + 16384 + base);
            bfrag8 al = *(const bfrag8*)(lds + 32768 + base);
            const unsigned short* b0 = wsB + ((size_t)ch * 128 + e0) * 8;
            const unsigned short* b1 = b0 + 32 * 8;
            bfrag8 bh0 = *(const bfrag8*)(b0);
            bfrag8 bm0 = *(const bfrag8*)(b0 + 16384);
            bfrag8 bl0 = *(const bfrag8*)(b0 + 32768);
            bfrag8 bh1 = *(const bfrag8*)(b1);
            bfrag8 bm1 = *(const bfrag8*)(b1 + 16384);
            bfrag8 bl1 = *(const bfrag8*)(b1 + 32768);
            acc0 = MFMA32(al, bh0, acc0);  acc1 = MFMA32(al, bh1, acc1);
            acc0 = MFMA32(am, bm0, acc0);  acc1 = MFMA32(am, bm1, acc1);
            acc0 = MFMA32(ah, bl0, acc0);  acc1 = MFMA32(ah, bl1, acc1);
            acc0 = MFMA32(am, bh0, acc0);  acc1 = MFMA32(am, bh1, acc1);
            acc0 = MFMA32(ah, bm0, acc0);  acc1 = MFMA32(ah, bm1, acc1);
            acc0 = MFMA32(ah, bh0, acc0);  acc1 = MFMA32(ah, bh1, acc1);
        }
    }
    __syncthreads();   // all waves done reading A planes

    // ---- write x (swizzled) into A region; dots into dot_s ----
    float* xs = (float*)lds;                   // [64][128] swizzled
    float* dots = (float*)(lds + 49152);       // [64][16]
    #pragma unroll
    for (int r = 0; r < 4; ++r)
        dots[(16 * w + (lane >> 4) * 4 + r) * 16 + (lane & 15)] = dacc[r];
    {
        const int eb = 64 * np + (lane & 31);
        #pragma unroll
        for (int r = 0; r < 16; ++r) {
            int m = 32 * mt + (r & 3) + 8 * (r >> 2) + 4 * (lane >> 5);
            int x0i = eb ^ ((m & 7) << 2);
            int x1i = (eb + 32) ^ ((m & 7) << 2);
            xs[m * 128 + x0i] = acc0[r];
            xs[m * 128 + x1i] = acc1[r];
        }
    }
    __syncthreads();

    // ---- phase 2: p1/p2 reductions + EMG + wave-reduced segment atomics ----
    {
        const int m = tid >> 2;
        const int q = tid & 3;
        float p1 = 0.0f, p2 = 0.0f;
        #pragma unroll
        for (int i = 0; i < 8; ++i) {
            int eq = q * 8 + i;                 // logical float4-group
            int peq = eq ^ (m & 7);             // physical float4-group
            // physical float 4*peq+d holds LOGICAL feature 4*eq+d
            float4 x4 = *(const float4*)(xs + m * 128 + peq * 4);
            float4 w4 = *(const float4*)(invs2 + eq * 4);
            float s2 = x4.x * x4.x + x4.y * x4.y + x4.z * x4.z + x4.w * x4.w;
            p2 += s2;
            p1 += x4.x * x4.x * w4.x + x4.y * x4.y * w4.y
                + x4.z * x4.z * w4.z + x4.w * x4.w * w4.w;
        }
        p1 += __shfl_xor(p1, 1); p1 += __shfl_xor(p1, 2);
        p2 += __shfl_xor(p2, 1); p2 += __shfl_xor(p2, 2);
        int sv = seg[rblk + m];
        sv = (sv < 0) ? 0 : ((sv >= B) ? B - 1 : sv);

        float art[3];
        #pragma unroll
        for (int j = 0; j < 3; ++j) {
            int k = q + 4 * j;
            float dt = dots[m * 16 + k];
            float orth2 = p2 - dt * dt;
            float z = (pf[PP_AK + k] - dt) * pf[PP_ISQ + k];
            art[j] = pf[PP_OC + k] - orth2 * pf[PP_I2SA + k]
                   + pf[PP_LC + k] + logerfc_f(z)
                   + pf[PP_LT + k] * (pf[PP_M2 + k] - 2.0f * dt);
        }
        float nart = pf[PP_CNA] - 0.5f * p1;

        // wave covers 16 rows (m = 16w..16w+15). If they share one variant,
        // reduce across rows in-register and atomic once per (variant, col).
        int sv0 = __shfl(sv, lane & 3);       // first-row sv for this q
        bool uni = __all(sv == sv0);
        if (uni) {
            #pragma unroll
            for (int off = 4; off <= 32; off <<= 1) {
                art[0] += __shfl_xor(art[0], off);
                art[1] += __shfl_xor(art[1], off);
                art[2] += __shfl_xor(art[2], off);
                nart   += __shfl_xor(nart,   off);
            }
            if (lane < 4) {
                atomicAdd(accum + (size_t)sv * 16 + 1 + lane,     art[0]);
                atomicAdd(accum + (size_t)sv * 16 + 1 + lane + 4, art[1]);
                atomicAdd(accum + (size_t)sv * 16 + 1 + lane + 8, art[2]);
                if (lane == 0) atomicAdd(accum + (size_t)sv * 16, nart);
            }
        } else {
            #pragma unroll
            for (int j = 0; j < 3; ++j)
                atomicAdd(accum + (size_t)sv * 16 + 1 + q + 4 * j, art[j]);
            if (q == 0) atomicAdd(accum + (size_t)sv * 16, nart);
        }
    }
}

// ---------------------------------------------------------------------------
__global__ __launch_bounds__(64) void k_final(
    const float* __restrict__ accum, const float* __restrict__ pf,
    float* __restrict__ out, int B)
{
    int b = blockIdx.x * 64 + threadIdx.x;
    if (b >= B) return;
    const float4* a4 = (const float4*)(accum + (size_t)b * 16);
    float4 v0 = a4[0], v1 = a4[1], v2 = a4[2], v3 = a4[3];
    float av[16] = {v0.x, v0.y, v0.z, v0.w, v1.x, v1.y, v1.z, v1.w,
                    v2.x, v2.y, v2.z, v2.w, v3.x, v3.y, v3.z, v3.w};
    float na = av[0];
    float art[12];
    float m = -1e30f;
    #pragma unroll
    for (int k = 0; k < 12; ++k) {
        art[k] = av[1 + k] + pf[PP_LSM + k];
        m = fmaxf(m, art[k]);
    }
    float s = 0.0f;
    #pragma unroll
    for (int k = 0; k < 12; ++k) s += expf(art[k] - m);
    float lse = m + logf(s);
    float logit = lse - na;
    out[b] = 20.0f * tanhf(logit / 20.0f);
    float* lk = out + B + (size_t)b * 13;
    lk[0] = na;
    #pragma unroll
    for (int k = 0; k < 12; ++k) lk[1 + k] = art[k];
}

// ---------------------------------------------------------------------------
extern "C" void kernel_launch(void* const* d_in, const int* in_sizes, int n_in,
                              void* d_out, int out_size, void* d_ws, size_t ws_size,
                              hipStream_t stream) {
    const float* alt    = (const float*)d_in[0];
    // d_in[1] ref_re unused by reference output
    const float* trans  = (const float*)d_in[2];
    const float* rot    = (const float*)d_in[3];
    const float* stdev  = (const float*)d_in[4];
    const float* dirs   = (const float*)d_in[5];
    const float* mu     = (const float*)d_in[6];
    const float* sigma  = (const float*)d_in[7];
    const float* lam    = (const float*)d_in[8];
    const float* astd   = (const float*)d_in[9];
    const float* w      = (const float*)d_in[10];
    const int*   counts = (const int*)d_in[11];
    // d_in[12] ref_counts_b unused

    const int E = in_sizes[2];          // 128
    const int R = in_sizes[0] / E;      // 65536
    const int K = in_sizes[6];          // 12
    const int B = in_sizes[11];         // 4096

    float* out = (float*)d_out;

    // workspace layout (16B aligned segments)
    int*            seg   = (int*)d_ws;                           // R
    int*            offs  = seg + R;                              // B+1 (+pad)
    float*          invs2 = (float*)(offs + B + 16);              // E
    float*          pf    = invs2 + E;                            // PP_SIZE
    unsigned short* wsB   = (unsigned short*)(pf + PP_SIZE);      // 3*16*128*8
    unsigned short* wsV   = wsB + 3 * 16 * 128 * 8;               // 3*16*16*8
    float*          accum = (float*)(wsV + 3 * 16 * 16 * 8);      // B*16

    k_pre<<<25, 256, 0, stream>>>(rot, dirs, stdev, mu, sigma, lam, astd, w,
                                  counts, wsB, wsV, invs2, pf, offs, accum,
                                  B, R, E, K);
    k_seg<<<(B + 255) / 256, 256, 0, stream>>>(offs, counts, seg, B, R);
    k_main<<<R / 64, 256, 53248, stream>>>(alt, trans, wsB, wsV, invs2, pf,
                                           seg, accum, B);
    k_final<<<(B + 63) / 64, 64, 0, stream>>>(accum, pf, out, B);
}